// Round 1
// baseline (242.202 us; speedup 1.0000x reference)
//
#include <hip/hip_runtime.h>
#include <stdint.h>

// EnergyWell: for each of N instances, over C=64 wells compute
//   dx = max(xl-(x-hx), x+hx-xh, 0), dy likewise, dist = dx+dy (inf if !avail)
// pick argmin (first index on ties), energy = dx_sel^e + dy_sel^e (e==2.0).
//
// Layout: one WAVE per instance; lane c owns well c. Avail row read is the
// dominant traffic (N*64 int32 = 128 MB) and is perfectly coalesced this way.

#define C_WELLS 64

__global__ __launch_bounds__(256, 8)
void energy_well_kernel(const float* __restrict__ inst_pos,    // N*2
                        const float* __restrict__ half_sizes,  // N*2
                        const float* __restrict__ well_boxes,  // 64*4
                        const int*   __restrict__ avail,       // N*64 (nonzero = avail)
                        const float* __restrict__ exponents,   // N
                        float* __restrict__ out,               // N
                        int N)
{
    const int lane = threadIdx.x & 63;
    // wave-uniform id, forced into SGPR so per-instance scalar loads go s_load
    int waveId = __builtin_amdgcn_readfirstlane(
        (int)((blockIdx.x * blockDim.x + threadIdx.x) >> 6));
    const int nWaves = (gridDim.x * blockDim.x) >> 6;

    // each lane's well box (loaded once per wave): x=xl, y=yl, z=xh, w=yh
    const float4 box = ((const float4*)well_boxes)[lane];

    for (int i = waveId; i < N; i += nWaves) {
        // wave-uniform instance scalars
        const float x  = inst_pos[2 * i];
        const float y  = inst_pos[2 * i + 1];
        const float hx = half_sizes[2 * i];
        const float hy = half_sizes[2 * i + 1];
        const float e  = exponents[i];
        // coalesced: lane c reads avail[i*64 + c]
        const int av = avail[(size_t)i * C_WELLS + lane];

        const float dx = fmaxf(fmaxf(box.x - (x - hx), (x + hx) - box.z), 0.0f);
        const float dy = fmaxf(fmaxf(box.y - (y - hy), (y + hy) - box.w), 0.0f);
        float dist = dx + dy;
        dist = av ? dist : __builtin_inff();

        // exact wave-wide min (fmin is exact; no reassociation error)
        float m = dist;
        #pragma unroll
        for (int off = 32; off >= 1; off >>= 1)
            m = fminf(m, __shfl_xor(m, off, 64));

        // first lane achieving the min == jnp.argmin first-occurrence tie-break
        unsigned long long eq = __ballot(dist == m);
        const int w = __ffsll((long long)eq) - 1;

        const float dxs = __shfl(dx, w, 64);
        const float dys = __shfl(dy, w, 64);

        if (lane == 0) {
            float energy;
            if (e == 2.0f) {
                energy = dxs * dxs + dys * dys;
            } else {
                energy = powf(dxs, e) + powf(dys, e);
            }
            out[i] = energy;
        }
    }
}

extern "C" void kernel_launch(void* const* d_in, const int* in_sizes, int n_in,
                              void* d_out, int out_size, void* d_ws, size_t ws_size,
                              hipStream_t stream)
{
    // setup_inputs order:
    // 0: inst_pos (N*2 f32), 1: half_inst_sizes (N*2 f32), 2: inst_areas (N f32, UNUSED),
    // 3: well_boxes (64*4 f32), 4: inst_cr_avail_map (N*64 int), 5: exponents (N f32)
    const float* inst_pos   = (const float*)d_in[0];
    const float* half_sizes = (const float*)d_in[1];
    const float* well_boxes = (const float*)d_in[3];
    const int*   avail      = (const int*)d_in[4];
    const float* exponents  = (const float*)d_in[5];
    float* out = (float*)d_out;

    const int N = in_sizes[5];  // exponents has length N

    // 2048 blocks * 4 waves = 8192 waves; ~61 instances per wave; 32 waves/CU
    const int blocks = 2048;
    energy_well_kernel<<<dim3(blocks), dim3(256), 0, stream>>>(
        inst_pos, half_sizes, well_boxes, avail, exponents, out, N);
}

// Round 2
// 225.252 us; speedup vs baseline: 1.0752x; 1.0752x over previous
//
#include <hip/hip_runtime.h>
#include <stdint.h>

// EnergyWell, round 2: thread-per-instance with ballot-transposed avail masks.
//
// R1 post-mortem: wave-per-instance was latency-bound on the cross-lane
// reduction (ds_swizzle/ds_bpermute chains) — L3-warm dispatches took the
// same 100us as cold ones. This version has ZERO cross-lane ops in the hot
// loop: each thread owns an instance and scans all 64 wells in registers.
// The dominant input (avail, N*64 int32 = 128 MB) is still read perfectly
// coalesced via a ballot-transpose prologue: lane c reads row j's column c,
// __ballot packs row j into a 64-bit mask, lane j keeps it.

#define C_WELLS 64

__global__ __launch_bounds__(256, 8)
void energy_well_kernel(const float* __restrict__ inst_pos,    // N*2
                        const float* __restrict__ half_sizes,  // N*2
                        const float4* __restrict__ well_boxes, // 64 x {xl,yl,xh,yh}
                        const int*   __restrict__ avail,       // N*64
                        const float* __restrict__ exponents,   // N
                        float* __restrict__ out,               // N
                        int N, int nTiles)
{
    const int lane = threadIdx.x & 63;
    const int waveId = (int)((blockIdx.x * blockDim.x + threadIdx.x) >> 6);
    const int nWaves = (gridDim.x * blockDim.x) >> 6;

    for (int tile = waveId; tile < nTiles; tile += nWaves) {
        const int base = tile << 6;   // first instance of this tile
        const int i    = base + lane; // this thread's instance

        // ---- Phase 1: coalesced read of the tile's 64x64 avail block,
        //      transposed into per-thread 64-bit masks via ballot (SALU path,
        //      no LDS pipe). Full tile is the common case (uniform branch).
        unsigned long long myMask = 0ull;
        if (base + C_WELLS <= N) {
            #pragma unroll 16
            for (int j = 0; j < C_WELLS; ++j) {
                const int av = avail[(size_t)(base + j) * C_WELLS + lane];
                const unsigned long long m = __ballot(av != 0);
                if (lane == j) myMask = m;
            }
        } else {
            #pragma unroll 16
            for (int j = 0; j < C_WELLS; ++j) {
                int av = 0;
                if (base + j < N) av = avail[(size_t)(base + j) * C_WELLS + lane];
                const unsigned long long m = __ballot(av != 0);
                if (lane == j) myMask = m;
            }
        }

        // ---- Phase 2: per-thread scan of the 64 wells, running strict-< min
        //      (preserves jnp.argmin first-occurrence tie-break).
        float x = 0.f, y = 0.f, hx = 0.f, hy = 0.f, e = 2.0f;
        if (i < N) {
            const float2 p = ((const float2*)inst_pos)[i];   // coalesced 8B
            const float2 h = ((const float2*)half_sizes)[i]; // coalesced 8B
            x = p.x; y = p.y; hx = h.x; hy = h.y;
            e = exponents[i];
        }
        const float xm = x - hx, xp = x + hx;
        const float ym = y - hy, yp = y + hy;

        float best = __builtin_inff();
        float bdx = 0.0f, bdy = 0.0f;
        #pragma unroll
        for (int c = 0; c < C_WELLS; ++c) {
            const float4 box = well_boxes[c];  // wave-uniform -> s_load
            const float dx = fmaxf(fmaxf(box.x - xm, xp - box.z), 0.0f);
            const float dy = fmaxf(fmaxf(box.y - ym, yp - box.w), 0.0f);
            float dist = dx + dy;
            const bool av = (myMask >> c) & 1ull;
            dist = av ? dist : __builtin_inff();
            if (dist < best) { best = dist; bdx = dx; bdy = dy; }
        }

        if (i < N) {
            float energy;
            if (e == 2.0f) energy = bdx * bdx + bdy * bdy;
            else           energy = powf(bdx, e) + powf(bdy, e);
            out[i] = energy;
        }
    }
}

extern "C" void kernel_launch(void* const* d_in, const int* in_sizes, int n_in,
                              void* d_out, int out_size, void* d_ws, size_t ws_size,
                              hipStream_t stream)
{
    // 0: inst_pos (N*2 f32), 1: half_inst_sizes (N*2 f32), 2: inst_areas (UNUSED),
    // 3: well_boxes (64*4 f32), 4: inst_cr_avail_map (N*64 int), 5: exponents (N f32)
    const float*  inst_pos   = (const float*)d_in[0];
    const float*  half_sizes = (const float*)d_in[1];
    const float4* well_boxes = (const float4*)d_in[3];
    const int*    avail      = (const int*)d_in[4];
    const float*  exponents  = (const float*)d_in[5];
    float* out = (float*)d_out;

    const int N = in_sizes[5];
    const int nTiles = (N + C_WELLS - 1) / C_WELLS;           // 7813
    const int wavesNeeded = nTiles;                           // one tile per wave
    const int blocks = (wavesNeeded + 3) / 4;                 // 4 waves/block

    energy_well_kernel<<<dim3(blocks), dim3(256), 0, stream>>>(
        inst_pos, half_sizes, well_boxes, avail, exponents, out, N, nTiles);
}

// Round 3
// 209.116 us; speedup vs baseline: 1.1582x; 1.0772x over previous
//
#include <hip/hip_runtime.h>
#include <stdint.h>

// EnergyWell, round 3: thread-per-instance + ballot-transpose (from R2), plus:
//  - well grid is separable: well c=(iy*8+ix) has edges xl[ix],xh[ix],yl[iy],yh[iy].
//    Load the 8+8 edge pairs ONCE per wave (uniform s_load, hoisted) -> no
//    per-well SMEM loads/waits in the hot loop (R2's hidden stall).
//  - per instance precompute dxv[8], dyv[8] (v_max3), then dist = dxv+dyv (1 add).
//  - avail bit via compile-time bfe on 32-bit mask halves; avail folded into
//    the min-update predicate (SALU s_and_b64) instead of a cndmask-to-inf.

#define C_WELLS 64
#define GX 8
#define GY 8

__global__ __launch_bounds__(256, 8)
void energy_well_kernel(const float* __restrict__ inst_pos,    // N*2
                        const float* __restrict__ half_sizes,  // N*2
                        const float* __restrict__ well_boxes,  // 64*4: {xl,yl,xh,yh}
                        const int*   __restrict__ avail,       // N*64
                        const float* __restrict__ exponents,   // N
                        float* __restrict__ out,               // N
                        int N, int nTiles)
{
    const int lane = threadIdx.x & 63;
    const int waveId = (int)((blockIdx.x * blockDim.x + threadIdx.x) >> 6);
    const int nWaves = (gridDim.x * blockDim.x) >> 6;

    // Loop-invariant, wave-uniform edge tables (compile-time offsets -> s_load,
    // hoisted once per wave; 32 SGPRs).
    float xlv[GX], xhv[GX], ylv[GY], yhv[GY];
    #pragma unroll
    for (int ix = 0; ix < GX; ++ix) {
        xlv[ix] = well_boxes[4 * ix + 0];
        xhv[ix] = well_boxes[4 * ix + 2];
    }
    #pragma unroll
    for (int iy = 0; iy < GY; ++iy) {
        ylv[iy] = well_boxes[4 * (GX * iy) + 1];
        yhv[iy] = well_boxes[4 * (GX * iy) + 3];
    }

    for (int tile = waveId; tile < nTiles; tile += nWaves) {
        const int base = tile << 6;
        const int i    = base + lane;

        // ---- Phase 1: ballot-transpose of the tile's 64x64 avail block.
        // Lane c reads row j col c (coalesced 256B/instr); ballot packs row j
        // into an SGPR pair; lane j keeps it (v_writelane-able select).
        unsigned long long myMask = 0ull;
        if (base + C_WELLS <= N) {
            #pragma unroll 16
            for (int j = 0; j < C_WELLS; ++j) {
                const int av = avail[(size_t)(base + j) * C_WELLS + lane];
                const unsigned long long m = __ballot(av != 0);
                if (lane == j) myMask = m;
            }
        } else {
            #pragma unroll 16
            for (int j = 0; j < C_WELLS; ++j) {
                int av = 0;
                if (base + j < N) av = avail[(size_t)(base + j) * C_WELLS + lane];
                const unsigned long long m = __ballot(av != 0);
                if (lane == j) myMask = m;
            }
        }

        // ---- Phase 2: per-thread scan, separable distances.
        float x = 0.f, y = 0.f, hx = 0.f, hy = 0.f, e = 2.0f;
        if (i < N) {
            const float2 p = ((const float2*)inst_pos)[i];
            const float2 h = ((const float2*)half_sizes)[i];
            x = p.x; y = p.y; hx = h.x; hy = h.y;
            e = exponents[i];
        }
        const float xm = x - hx, xp = x + hx;
        const float ym = y - hy, yp = y + hy;

        float dxv[GX], dyv[GY];
        #pragma unroll
        for (int ix = 0; ix < GX; ++ix)
            dxv[ix] = fmaxf(fmaxf(xlv[ix] - xm, xp - xhv[ix]), 0.0f);  // v_max3
        #pragma unroll
        for (int iy = 0; iy < GY; ++iy)
            dyv[iy] = fmaxf(fmaxf(ylv[iy] - ym, yp - yhv[iy]), 0.0f);

        const unsigned mlo = (unsigned)(myMask & 0xffffffffull);
        const unsigned mhi = (unsigned)(myMask >> 32);

        float best = __builtin_inff();
        float bdx = 0.0f, bdy = 0.0f;
        #pragma unroll
        for (int c = 0; c < C_WELLS; ++c) {
            const int ix = c & 7, iy = c >> 3;
            const float dist = dxv[ix] + dyv[iy];                 // 1 add
            const unsigned bit = (c < 32) ? ((mlo >> c) & 1u)     // v_bfe (const c)
                                          : ((mhi >> (c - 32)) & 1u);
            const bool upd = bit && (dist < best);                // 2 v_cmp + s_and
            best = upd ? dist    : best;                          // strict '<' keeps
            bdx  = upd ? dxv[ix] : bdx;                           // first index on
            bdy  = upd ? dyv[iy] : bdy;                           // ties (argmin)
        }

        if (i < N) {
            float energy;
            if (e == 2.0f) energy = bdx * bdx + bdy * bdy;
            else           energy = powf(bdx, e) + powf(bdy, e);
            out[i] = energy;
        }
    }
}

extern "C" void kernel_launch(void* const* d_in, const int* in_sizes, int n_in,
                              void* d_out, int out_size, void* d_ws, size_t ws_size,
                              hipStream_t stream)
{
    // 0: inst_pos (N*2 f32), 1: half_inst_sizes (N*2 f32), 2: inst_areas (UNUSED),
    // 3: well_boxes (64*4 f32), 4: inst_cr_avail_map (N*64 int), 5: exponents (N f32)
    const float* inst_pos   = (const float*)d_in[0];
    const float* half_sizes = (const float*)d_in[1];
    const float* well_boxes = (const float*)d_in[3];
    const int*   avail      = (const int*)d_in[4];
    const float* exponents  = (const float*)d_in[5];
    float* out = (float*)d_out;

    const int N = in_sizes[5];
    const int nTiles = (N + C_WELLS - 1) / C_WELLS;   // 7813
    const int blocks = (nTiles + 3) / 4;              // 4 waves/block, 1 tile/wave

    energy_well_kernel<<<dim3(blocks), dim3(256), 0, stream>>>(
        inst_pos, half_sizes, well_boxes, avail, exponents, out, N, nTiles);
}

// Round 4
// 199.205 us; speedup vs baseline: 1.2158x; 1.0498x over previous
//
#include <hip/hip_runtime.h>
#include <stdint.h>

// EnergyWell, round 4: 4-lanes-per-instance, no transpose, software-pipelined.
//
// R3 post-mortem: ballot-transpose cost ~550 VALU + 64 VMEM per tile and,
// with one tile per wave, every wave stalled in lockstep on the same
// load->ballot chains (convoy; 70% idle at 29% VALUBusy). This version:
//  - lane sub = lane&3 owns wells [16*sub, 16*sub+16) of instance lane>>4...
//    (instance = base + (lane>>2)); avail arrives via int4 loads directly in
//    the consuming lane: 4 VMEM instrs / 16 instances, zero ballots.
//  - separable grid: xl/xh[8] are wave-uniform s_loads; each lane needs only
//    its two iy rows' yl/yh (4 per-lane loads, hoisted).
//  - cross-lane argmin over the 4 subs via monotone 34-bit key
//    (float_bits(dist)<<2 | sub): exact, first-index tie-break preserved.
//  - persistent waves + explicit next-tile register prefetch: loads for tile
//    t+1 are in flight while tile t computes (breaks the convoy).

#define C_WELLS 64

struct TileWork {
    int4   av[4];   // this lane's 16 avail words (wells 16*sub .. 16*sub+15)
    float2 p, h;    // instance pos / half sizes (duplicated across 4 lanes)
    float  e;       // exponent
};

__device__ __forceinline__ TileWork load_tile(
    const int4* __restrict__ avail4, const float2* __restrict__ inst_pos,
    const float2* __restrict__ half_sizes, const float* __restrict__ exponents,
    int tile, int lane, int N)
{
    TileWork w;
    const int i  = tile * 16 + (lane >> 2);
    const int ii = i < N ? i : N - 1;          // clamp (tail safety)
    // avail4 element idx = ii*16 + sub*4 + j; for full tiles this equals
    // tile*256 + 4*lane + j -> lanes stride 64B, 4 instrs reuse the same
    // 32 cache lines of the tile's 4KB block.
    const int4* a = avail4 + ((size_t)ii * 16 + (size_t)(lane & 3) * 4);
    w.av[0] = a[0]; w.av[1] = a[1]; w.av[2] = a[2]; w.av[3] = a[3];
    w.p = inst_pos[ii];
    w.h = half_sizes[ii];
    w.e = exponents[ii];
    return w;
}

__global__ __launch_bounds__(256, 4)
void energy_well_kernel(const float2* __restrict__ inst_pos,   // N
                        const float2* __restrict__ half_sizes, // N
                        const float*  __restrict__ well_boxes, // 64*4 {xl,yl,xh,yh}
                        const int4*   __restrict__ avail4,     // N*16
                        const float*  __restrict__ exponents,  // N
                        float* __restrict__ out,               // N
                        int N, int nT16)
{
    const int lane = threadIdx.x & 63;
    const int sub  = lane & 3;                 // well-quarter owner
    const int waveId = (int)((blockIdx.x * blockDim.x + threadIdx.x) >> 6);
    const int nWaves = (gridDim.x * blockDim.x) >> 6;

    // x-edges: wave-uniform, compile-time offsets -> s_load, hoisted (16 SGPR)
    float xlv[8], xhv[8];
    #pragma unroll
    for (int ix = 0; ix < 8; ++ix) {
        xlv[ix] = well_boxes[4 * ix + 0];
        xhv[ix] = well_boxes[4 * ix + 2];
    }
    // this lane's two y-rows (iy = 2*sub, 2*sub+1): 4 per-lane loads, hoisted
    const float ylA = well_boxes[64 * sub + 1];
    const float yhA = well_boxes[64 * sub + 3];
    const float ylB = well_boxes[64 * sub + 33];
    const float yhB = well_boxes[64 * sub + 35];

    int tile = waveId;
    if (tile >= nT16) return;

    TileWork w = load_tile(avail4, inst_pos, half_sizes, exponents, tile, lane, N);

    while (true) {
        const int nt = tile + nWaves;
        TileWork wn;
        const bool more = nt < nT16;
        if (more)  // wave-uniform; issues next tile's loads before compute
            wn = load_tile(avail4, inst_pos, half_sizes, exponents, nt, lane, N);

        // ---- compute current tile ----
        const float xm = w.p.x - w.h.x, xp_ = w.p.x + w.h.x;
        const float ym = w.p.y - w.h.y, yp_ = w.p.y + w.h.y;

        float dxv[8];
        #pragma unroll
        for (int ix = 0; ix < 8; ++ix)
            dxv[ix] = fmaxf(fmaxf(xlv[ix] - xm, xp_ - xhv[ix]), 0.0f); // v_max3
        const float dyA = fmaxf(fmaxf(ylA - ym, yp_ - yhA), 0.0f);
        const float dyB = fmaxf(fmaxf(ylB - ym, yp_ - yhB), 0.0f);

        float best = __builtin_inff();
        float bdx = 0.0f, bdy = 0.0f;
        #pragma unroll
        for (int j = 0; j < 4; ++j) {
            const int4 a4 = w.av[j];
            #pragma unroll
            for (int k = 0; k < 4; ++k) {
                const int c2 = 4 * j + k;                    // 0..15, ascending c
                const int av = (k == 0) ? a4.x : (k == 1) ? a4.y
                             : (k == 2) ? a4.z : a4.w;
                const int   ix = c2 & 7;
                const float dy = (c2 < 8) ? dyA : dyB;
                const float dist = dxv[ix] + dy;
                const bool upd = (av != 0) && (dist < best);  // strict '<': first idx
                best = upd ? dist    : best;
                bdx  = upd ? dxv[ix] : bdx;
                bdy  = upd ? dy      : bdy;
            }
        }

        // ---- cross-sub argmin: monotone key (bits(best)<<2)|sub, exact ----
        const unsigned kb  = __float_as_uint(best);          // best >= 0
        unsigned klo = (kb << 2) | (unsigned)sub;
        unsigned khi = kb >> 30;
        const unsigned mylo = klo, myhi = khi;
        #pragma unroll
        for (int off = 1; off <= 2; off <<= 1) {
            const unsigned plo = __shfl_xor(klo, off, 64);
            const unsigned phi = __shfl_xor(khi, off, 64);
            const bool less = (phi < khi) || (phi == khi && plo < klo);
            klo = less ? plo : klo;
            khi = less ? phi : khi;
        }
        const bool winner = (khi == myhi) && (klo == mylo);  // unique (sub in key)

        const int i = tile * 16 + (lane >> 2);
        if (winner && i < N) {
            float energy;
            if (w.e == 2.0f) energy = bdx * bdx + bdy * bdy;
            else             energy = powf(bdx, w.e) + powf(bdy, w.e);
            out[i] = energy;
        }

        if (!more) break;
        w = wn;
        tile = nt;
    }
}

extern "C" void kernel_launch(void* const* d_in, const int* in_sizes, int n_in,
                              void* d_out, int out_size, void* d_ws, size_t ws_size,
                              hipStream_t stream)
{
    // 0: inst_pos (N*2 f32), 1: half_inst_sizes (N*2 f32), 2: inst_areas (UNUSED),
    // 3: well_boxes (64*4 f32), 4: inst_cr_avail_map (N*64 int), 5: exponents (N)
    const float2* inst_pos   = (const float2*)d_in[0];
    const float2* half_sizes = (const float2*)d_in[1];
    const float*  well_boxes = (const float*)d_in[3];
    const int4*   avail4     = (const int4*)d_in[4];
    const float*  exponents  = (const float*)d_in[5];
    float* out = (float*)d_out;

    const int N = in_sizes[5];
    const int nT16 = (N + 15) / 16;        // 16-instance tiles (31250)

    // persistent: 1024 blocks * 4 waves = 4096 waves, ~7.6 tiles each;
    // launch_bounds(256,4) -> 128 VGPR cap, 16 waves/CU
    const int blocks = 1024;
    energy_well_kernel<<<dim3(blocks), dim3(256), 0, stream>>>(
        inst_pos, half_sizes, well_boxes, avail4, exponents, out, N, nT16);
}

// Round 5
// 196.333 us; speedup vs baseline: 1.2336x; 1.0146x over previous
//
#include <hip/hip_runtime.h>
#include <stdint.h>

// EnergyWell, round 5: quad-per-instance, 64-bit-key argmin, DPP reduce.
//
// R4 post-mortem: still chain-bound. The per-tile serial path was the 16-step
// best cmp+cndmask chain (~128cyc) plus 4 dependent ds_swizzle (~120cyc each,
// LDS pipe) for the cross-sub butterfly, with only 16 waves/CU to hide it.
// This version:
//  - monotone 38-bit key in u64: (float_bits(dist)<<6)|well_idx. Exact:
//    dist>=0 so bits are order-preserving; tie -> lowest well idx (jnp.argmin).
//    Min = v_cmp_lt_u64 + 2 cndmask. Scan = 4 parallel chains of 4 + tree
//    merge (depth ~6, not 16).
//  - cross-sub reduce via DPP quad_perm (VALU pipe, no LDS): lanes 4i..4i+3
//    are the quad owning instance i; xor1=0xB1, xor2=0x4E.
//  - one 16-instance tile per wave, 31250 waves: latency hidden by wave churn;
//    launch_bounds(256,6) -> 24 waves/CU.

#define C_WELLS 64

template <int CTRL>
__device__ __forceinline__ unsigned long long dpp64(unsigned long long k) {
    int lo = (int)(unsigned)k;
    int hi = (int)(unsigned)(k >> 32);
    lo = __builtin_amdgcn_update_dpp(0, lo, CTRL, 0xF, 0xF, true);
    hi = __builtin_amdgcn_update_dpp(0, hi, CTRL, 0xF, 0xF, true);
    return ((unsigned long long)(unsigned)hi << 32) | (unsigned)lo;
}

__device__ __forceinline__ unsigned long long umin64(unsigned long long a,
                                                     unsigned long long b) {
    return a < b ? a : b;   // v_cmp_lt_u64 + 2 cndmask
}

__global__ __launch_bounds__(256, 6)
void energy_well_kernel(const float2* __restrict__ inst_pos,   // N
                        const float2* __restrict__ half_sizes, // N
                        const float*  __restrict__ well_boxes, // 64*4 {xl,yl,xh,yh}
                        const int4*   __restrict__ avail4,     // N*16
                        const float*  __restrict__ exponents,  // N
                        float* __restrict__ out,               // N
                        int N, int nT16)
{
    const int lane = threadIdx.x & 63;
    const int sub  = lane & 3;                 // quad member: wells [16sub,16sub+16)
    const int tile = (int)((blockIdx.x * blockDim.x + threadIdx.x) >> 6);
    if (tile >= nT16) return;

    const int i  = tile * 16 + (lane >> 2);    // this quad's instance
    const int ii = i < N ? i : N - 1;          // clamp (tail safety)

    // ---- issue all loads up front (7 VMEM, independent) ----
    const int4* a = avail4 + ((size_t)ii * 16 + (size_t)sub * 4);
    const int4 av0 = a[0], av1 = a[1], av2 = a[2], av3 = a[3];
    const float2 p = inst_pos[ii];
    const float2 h = half_sizes[ii];
    const float  e = exponents[ii];

    // x-edges: wave-uniform, compile-time offsets -> s_load (16 SGPR)
    float xlv[8], xhv[8];
    #pragma unroll
    for (int ix = 0; ix < 8; ++ix) {
        xlv[ix] = well_boxes[4 * ix + 0];
        xhv[ix] = well_boxes[4 * ix + 2];
    }
    // this lane's two y-rows (iy = 2*sub, 2*sub+1)
    const float ylA = well_boxes[64 * sub + 1];
    const float yhA = well_boxes[64 * sub + 3];
    const float ylB = well_boxes[64 * sub + 33];
    const float yhB = well_boxes[64 * sub + 35];

    // ---- per-instance separable distances ----
    const float xm = p.x - h.x, xp_ = p.x + h.x;
    const float ym = p.y - h.y, yp_ = p.y + h.y;

    float dxv[8];
    #pragma unroll
    for (int ix = 0; ix < 8; ++ix)
        dxv[ix] = fmaxf(fmaxf(xlv[ix] - xm, xp_ - xhv[ix]), 0.0f);  // v_max3
    const float dyA = fmaxf(fmaxf(ylA - ym, yp_ - yhA), 0.0f);
    const float dyB = fmaxf(fmaxf(ylB - ym, yp_ - yhB), 0.0f);

    // ---- keyed scan: 4 independent chains of 4, then tree merge ----
    const unsigned gbase = (unsigned)(sub << 4);
    unsigned long long gm[4];
    #pragma unroll
    for (int j = 0; j < 4; ++j) {
        const int4 a4 = (j == 0) ? av0 : (j == 1) ? av1 : (j == 2) ? av2 : av3;
        unsigned long long acc = ~0ull;
        #pragma unroll
        for (int k = 0; k < 4; ++k) {
            const int c2 = 4 * j + k;                   // local well 0..15
            const int avw = (k == 0) ? a4.x : (k == 1) ? a4.y
                          : (k == 2) ? a4.z : a4.w;
            const float dy   = (c2 < 8) ? dyA : dyB;
            const float dist = dxv[c2 & 7] + dy;
            unsigned long long key =
                (((unsigned long long)__float_as_uint(dist)) << 6)
                | (unsigned long long)(gbase + (unsigned)c2);
            key = avw ? key : ~0ull;                    // mask unavailable
            acc = umin64(acc, key);
        }
        gm[j] = acc;
    }
    unsigned long long kmin = umin64(umin64(gm[0], gm[1]), umin64(gm[2], gm[3]));

    // ---- cross-sub (quad) reduce on the VALU pipe via DPP ----
    kmin = umin64(kmin, dpp64<0xB1>(kmin));   // quad_perm [1,0,3,2] : xor 1
    kmin = umin64(kmin, dpp64<0x4E>(kmin));   // quad_perm [2,3,0,1] : xor 2

    // ---- decode winner and store ----
    const int g = (int)(kmin & 63);           // global well index of the min
    const int s = g & 7;                      // ix
    float a0 = (s & 1) ? dxv[1] : dxv[0];
    float a1 = (s & 1) ? dxv[3] : dxv[2];
    float a2 = (s & 1) ? dxv[5] : dxv[4];
    float a3 = (s & 1) ? dxv[7] : dxv[6];
    float b0 = (s & 2) ? a1 : a0;
    float b1 = (s & 2) ? a3 : a2;
    const float dxs = (s & 4) ? b1 : b0;
    const float dys = (g & 8) ? dyB : dyA;    // valid on the winner's sub

    if (((g >> 4) == sub) && (i < N)) {       // unique winner lane per quad
        float energy;
        if (e == 2.0f) energy = dxs * dxs + dys * dys;
        else           energy = powf(dxs, e) + powf(dys, e);
        out[i] = energy;
    }
}

extern "C" void kernel_launch(void* const* d_in, const int* in_sizes, int n_in,
                              void* d_out, int out_size, void* d_ws, size_t ws_size,
                              hipStream_t stream)
{
    // 0: inst_pos (N*2 f32), 1: half_inst_sizes (N*2 f32), 2: inst_areas (UNUSED),
    // 3: well_boxes (64*4 f32), 4: inst_cr_avail_map (N*64 int), 5: exponents (N)
    const float2* inst_pos   = (const float2*)d_in[0];
    const float2* half_sizes = (const float2*)d_in[1];
    const float*  well_boxes = (const float*)d_in[3];
    const int4*   avail4     = (const int4*)d_in[4];
    const float*  exponents  = (const float*)d_in[5];
    float* out = (float*)d_out;

    const int N = in_sizes[5];
    const int nT16 = (N + 15) / 16;            // one 16-instance tile per wave
    const int blocks = (nT16 + 3) / 4;         // 4 waves/block

    energy_well_kernel<<<dim3(blocks), dim3(256), 0, stream>>>(
        inst_pos, half_sizes, well_boxes, avail4, exponents, out, N, nT16);
}